// Round 4
// baseline (566.943 us; speedup 1.0000x reference)
//
#include <hip/hip_runtime.h>
#include <stdint.h>

#define NTOK 4096
#define DD 1024
#define HH 2048
#define NE 8
#define CAP 4096

typedef short bf16x8 __attribute__((ext_vector_type(8)));
typedef float f32x4 __attribute__((ext_vector_type(4)));
typedef unsigned short u16;
typedef unsigned int u32;

__device__ __forceinline__ u16 f2b(float f){
    union { float f; u32 u; } v; v.f = f;
    return (u16)((v.u + 0x7fffu + ((v.u >> 16) & 1u)) >> 16);
}
__device__ __forceinline__ u32 pk2(float a, float b){
    return (u32)f2b(a) | ((u32)f2b(b) << 16);
}
// async global->LDS, 16B per lane; LDS dest = wave-uniform base + lane*16
__device__ __forceinline__ void gload16(const u16* g, u16* l){
    __builtin_amdgcn_global_load_lds((const __attribute__((address_space(1))) u32*)g,
                                     (__attribute__((address_space(3))) u32*)l, 16, 0, 0);
}

// ---------------- fp32 -> bf16 bulk converts (x, W1, W2, W3) ----------------
__global__ __launch_bounds__(256) void cvt_all_kernel(const float* __restrict__ x,
        const float* __restrict__ W1, const float* __restrict__ W2, const float* __restrict__ W3,
        u16* __restrict__ xb, u16* __restrict__ w1b, u16* __restrict__ w2b, u16* __restrict__ w3b){
    int y = blockIdx.y;
    const float* s; u16* d; int n4;
    if (y == 0){ s = x;  d = xb;  n4 = NTOK * DD / 4; }
    else if (y == 1){ s = W1; d = w1b; n4 = NE * HH * DD / 4; }
    else if (y == 2){ s = W2; d = w2b; n4 = NE * HH * DD / 4; }
    else { s = W3; d = w3b; n4 = NE * HH * DD / 4; }
    int i = blockIdx.x * 256 + threadIdx.x;
    if (i >= n4) return;
    float4 v = reinterpret_cast<const float4*>(s)[i];
    ushort4 o; o.x = f2b(v.x); o.y = f2b(v.y); o.z = f2b(v.z); o.w = f2b(v.w);
    reinterpret_cast<ushort4*>(d)[i] = o;
}

// ---------------- router (fp32, block-aggregated atomics) ----------------
__global__ __launch_bounds__(256) void router_kernel(const float* __restrict__ x,
                              const float* __restrict__ Wr,
                              int* __restrict__ cnt, int* __restrict__ list,
                              float* __restrict__ glist, float* __restrict__ psum,
                              int* __restrict__ cnt1, int* __restrict__ islot){
    __shared__ float wS[NE * DD];
    __shared__ float psumS[NE];
    __shared__ int cnt1S[NE], cntS[NE], baseS[NE];
    __shared__ int tE[32], tL[32];
    __shared__ float tP[32];
    int tid = threadIdx.x;
    for (int i = tid; i < NE * DD / 4; i += 256)
        reinterpret_cast<float4*>(wS)[i] = reinterpret_cast<const float4*>(Wr)[i];
    if (tid < NE){ psumS[tid] = 0.f; cnt1S[tid] = 0; cntS[tid] = 0; }
    __syncthreads();
    int lane = tid & 63, w = tid >> 6;
    for (int t = 0; t < 4; ++t){
        int li = w * 4 + t;
        int n = blockIdx.x * 16 + li;
        const float4* xr = reinterpret_cast<const float4*>(x + (size_t)n * DD);
        float acc[NE];
        #pragma unroll
        for (int e = 0; e < NE; ++e) acc[e] = 0.f;
        #pragma unroll
        for (int j = 0; j < 4; ++j){
            float4 xv = xr[lane + 64 * j];
            #pragma unroll
            for (int e = 0; e < NE; ++e){
                float4 wv = reinterpret_cast<const float4*>(wS + e * DD)[lane + 64 * j];
                acc[e] += xv.x * wv.x + xv.y * wv.y + xv.z * wv.z + xv.w * wv.w;
            }
        }
        #pragma unroll
        for (int e = 0; e < NE; ++e){
            float v = acc[e];
            #pragma unroll
            for (int s = 32; s > 0; s >>= 1) v += __shfl_xor(v, s);
            acc[e] = v;
        }
        if (lane == 0){
            float mx = acc[0];
            #pragma unroll
            for (int e = 1; e < NE; ++e) mx = fmaxf(mx, acc[e]);
            float p[NE], sm = 0.f;
            #pragma unroll
            for (int e = 0; e < NE; ++e){ p[e] = expf(acc[e] - mx); sm += p[e]; }
            float inv = 1.f / sm;
            #pragma unroll
            for (int e = 0; e < NE; ++e){ p[e] *= inv; atomicAdd(&psumS[e], p[e]); }
            int i0 = 0;
            #pragma unroll
            for (int e = 1; e < NE; ++e) if (acc[e] > acc[i0]) i0 = e;
            int i1 = -1;
            #pragma unroll
            for (int e = 0; e < NE; ++e) if (e != i0 && (i1 < 0 || acc[e] > acc[i1])) i1 = e;
            atomicAdd(&cnt1S[i0], 1);
            int l0 = atomicAdd(&cntS[i0], 1);
            int l1 = atomicAdd(&cntS[i1], 1);
            tE[li * 2] = i0; tE[li * 2 + 1] = i1;
            tP[li * 2] = p[i0]; tP[li * 2 + 1] = p[i1];
            tL[li * 2] = l0; tL[li * 2 + 1] = l1;
        }
    }
    __syncthreads();
    if (tid < NE){
        baseS[tid] = atomicAdd(&cnt[tid], cntS[tid]);
        atomicAdd(&psum[tid], psumS[tid]);
        atomicAdd(&cnt1[tid], cnt1S[tid]);
    }
    __syncthreads();
    if (tid < 32){
        int e = tE[tid], pos = baseS[e] + tL[tid];
        int n = blockIdx.x * 16 + (tid >> 1);
        list[e * CAP + pos]  = n;
        glist[e * CAP + pos] = tP[tid];
        islot[n * 2 + (tid & 1)] = e * CAP + pos;
    }
}

// ---------------- prefix offsets + aux loss ----------------
__global__ void finalize_kernel(const int* __restrict__ cnt, int* __restrict__ offs,
                                const float* __restrict__ psum, const int* __restrict__ cnt1,
                                float* __restrict__ aux_out){
    if (threadIdx.x == 0 && blockIdx.x == 0){
        int o = 0; float aux = 0.f;
        for (int e = 0; e < NE; ++e){
            offs[e] = o; o += cnt[e];
            aux += ((float)cnt1[e] * (1.f / NTOK)) * (psum[e] * (1.f / NTOK));
        }
        aux_out[0] = 0.01f * aux * (float)NE;
    }
}

// ---------------- GEMM1: h = silu(X W1^T) * (X W3^T) ----------------
// 128x128x64 tiles, XOR-swizzled LDS (pre-swizzled global source, swizzled read),
// global_load_lds staging, XCD swizzle (expert per XCD, mt-fastest)
template<int BW>
__global__ __launch_bounds__(256, 3) void ffn1_kernel(const u16* __restrict__ xb,
        const u16* __restrict__ w1b, const u16* __restrict__ w3b,
        const float* __restrict__ W1f, const float* __restrict__ W3f,
        const int* __restrict__ cnt, const int* __restrict__ offs,
        const int* __restrict__ list, u16* __restrict__ hbuf){
    int bid = blockIdx.x;                       // 4096 = 8e * 16n * 32mt
    int widx = (bid & 7) * 512 + (bid >> 3);    // bijective: XCD bid%8 gets 512 consecutive work items
    int e = widx >> 9, n0t = (widx >> 5) & 15, mt = widx & 31;
    int rows = cnt[e];
    int m0 = mt * 128;
    if (m0 >= rows) return;
    int n0 = n0t * 128;

    __shared__ u16 aS[128 * 64];
    __shared__ u16 b1S[128 * 64];
    __shared__ u16 b3S[128 * 64];

    int tid = threadIdx.x, lane = tid & 63, w = tid >> 6;
    int wm = (w & 1) * 64, wn = (w >> 1) * 64;
    int fr = lane & 15, fg = lane >> 4;
    int fr7 = fr & 7;
    int rc = lane >> 3;                          // row-in-chunk (0..7)
    int ce = ((lane & 7) ^ rc) * 8;              // XOR-swizzled source col (16B units)

    const u16* aptr[4];
    #pragma unroll
    for (int q = 0; q < 4; ++q){
        int r = m0 + (w * 4 + q) * 8 + rc;
        int tok = list[e * CAP + (r < rows ? r : rows - 1)];
        aptr[q] = xb + (size_t)tok * DD + ce;
    }
    size_t brow = (size_t)(e * HH + n0 + w * 32 + rc) * DD + ce;
    const u16*   b1p  = w1b + brow;
    const u16*   b3p  = w3b + brow;
    const float* b1pf = W1f + brow;
    const float* b3pf = W3f + brow;
    u16* aL  = aS  + w * 4 * 512;               // chunk = 8 rows x 64 cols = 512 elems (1KB)
    u16* b1L = b1S + w * 4 * 512;
    u16* b3L = b3S + w * 4 * 512;

    f32x4 acc1[4][4], acc3[4][4];
    #pragma unroll
    for (int mi = 0; mi < 4; ++mi)
        #pragma unroll
        for (int ni = 0; ni < 4; ++ni)
            #pragma unroll
            for (int j = 0; j < 4; ++j){ acc1[mi][ni][j] = 0.f; acc3[mi][ni][j] = 0.f; }

    for (int k0 = 0; k0 < DD; k0 += 64){
        #pragma unroll
        for (int q = 0; q < 4; ++q){
            gload16(aptr[q] + k0, aL + q * 512);
            if (BW){
                gload16(b1p + q * 8 * DD + k0, b1L + q * 512);
                gload16(b3p + q * 8 * DD + k0, b3L + q * 512);
            } else {
                const float* s1 = b1pf + q * 8 * DD + k0;
                float4 f0 = reinterpret_cast<const float4*>(s1)[0];
                float4 f1 = reinterpret_cast<const float4*>(s1)[1];
                int4 v; v.x = pk2(f0.x,f0.y); v.y = pk2(f0.z,f0.w); v.z = pk2(f1.x,f1.y); v.w = pk2(f1.z,f1.w);
                *reinterpret_cast<int4*>(b1L + q * 512 + lane * 8) = v;
                const float* s3 = b3pf + q * 8 * DD + k0;
                float4 g0 = reinterpret_cast<const float4*>(s3)[0];
                float4 g1 = reinterpret_cast<const float4*>(s3)[1];
                int4 u; u.x = pk2(g0.x,g0.y); u.y = pk2(g0.z,g0.w); u.z = pk2(g1.x,g1.y); u.w = pk2(g1.z,g1.w);
                *reinterpret_cast<int4*>(b3L + q * 512 + lane * 8) = u;
            }
        }
        __syncthreads();

        #pragma unroll
        for (int ks = 0; ks < 2; ++ks){
            int sl = ((ks * 4 + fg) ^ fr7) * 8;  // swizzled 16B-slot within row
            bf16x8 a[4], b1[4], b3[4];
            #pragma unroll
            for (int mi = 0; mi < 4; ++mi)
                a[mi] = *reinterpret_cast<const bf16x8*>(&aS[(wm + mi * 16 + fr) * 64 + sl]);
            #pragma unroll
            for (int ni = 0; ni < 4; ++ni){
                b1[ni] = *reinterpret_cast<const bf16x8*>(&b1S[(wn + ni * 16 + fr) * 64 + sl]);
                b3[ni] = *reinterpret_cast<const bf16x8*>(&b3S[(wn + ni * 16 + fr) * 64 + sl]);
            }
            #pragma unroll
            for (int mi = 0; mi < 4; ++mi)
                #pragma unroll
                for (int ni = 0; ni < 4; ++ni){
                    acc1[mi][ni] = __builtin_amdgcn_mfma_f32_16x16x32_bf16(a[mi], b1[ni], acc1[mi][ni], 0, 0, 0);
                    acc3[mi][ni] = __builtin_amdgcn_mfma_f32_16x16x32_bf16(a[mi], b3[ni], acc3[mi][ni], 0, 0, 0);
                }
        }
        __syncthreads();
    }

    int hoff = offs[e];
    #pragma unroll
    for (int mi = 0; mi < 4; ++mi)
        #pragma unroll
        for (int ni = 0; ni < 4; ++ni)
            #pragma unroll
            for (int j = 0; j < 4; ++j){
                int r = wm + mi * 16 + fg * 4 + j;
                int tr = m0 + r;
                if (tr < rows){
                    int c = wn + ni * 16 + fr;
                    float v1 = acc1[mi][ni][j], v3 = acc3[mi][ni][j];
                    float hv = (v1 / (1.f + expf(-v1))) * v3;
                    hbuf[(size_t)(hoff + tr) * HH + n0 + c] = f2b(hv);
                }
            }
}

// ---------------- GEMM2: y = h W2^T -> ybuf (fp32, slot rows) ----------------
template<int BW>
__global__ __launch_bounds__(256, 4) void ffn2_kernel(const u16* __restrict__ hbuf,
        const u16* __restrict__ w2b, const float* __restrict__ W2f,
        const int* __restrict__ cnt, const int* __restrict__ offs,
        float* __restrict__ ybuf){
    int bid = blockIdx.x;                       // 2048 = 8e * 8n * 32mt
    int widx = (bid & 7) * 256 + (bid >> 3);
    int e = widx >> 8, n0t = (widx >> 5) & 7, mt = widx & 31;
    int rows = cnt[e];
    int m0 = mt * 128;
    if (m0 >= rows) return;
    int n0 = n0t * 128;

    __shared__ u16 aS[128 * 64];
    __shared__ u16 bS[128 * 64];

    int tid = threadIdx.x, lane = tid & 63, w = tid >> 6;
    int wm = (w & 1) * 64, wn = (w >> 1) * 64;
    int fr = lane & 15, fg = lane >> 4;
    int fr7 = fr & 7;
    int rc = lane >> 3;
    int ce = ((lane & 7) ^ rc) * 8;

    int hoff = offs[e];
    const u16* aptr[4];
    #pragma unroll
    for (int q = 0; q < 4; ++q){
        int r = m0 + (w * 4 + q) * 8 + rc;
        if (r >= rows) r = rows - 1;
        aptr[q] = hbuf + (size_t)(hoff + r) * HH + ce;
    }
    size_t brow = (size_t)(e * DD + n0 + w * 32 + rc) * HH + ce;
    const u16*   b2p  = w2b + brow;
    const float* b2pf = W2f + brow;
    u16* aL = aS + w * 4 * 512;
    u16* bL = bS + w * 4 * 512;

    f32x4 acc[4][4];
    #pragma unroll
    for (int mi = 0; mi < 4; ++mi)
        #pragma unroll
        for (int ni = 0; ni < 4; ++ni)
            #pragma unroll
            for (int j = 0; j < 4; ++j) acc[mi][ni][j] = 0.f;

    for (int k0 = 0; k0 < HH; k0 += 64){
        #pragma unroll
        for (int q = 0; q < 4; ++q){
            gload16(aptr[q] + k0, aL + q * 512);
            if (BW){
                gload16(b2p + q * 8 * HH + k0, bL + q * 512);
            } else {
                const float* s2 = b2pf + q * 8 * HH + k0;
                float4 f0 = reinterpret_cast<const float4*>(s2)[0];
                float4 f1 = reinterpret_cast<const float4*>(s2)[1];
                int4 v; v.x = pk2(f0.x,f0.y); v.y = pk2(f0.z,f0.w); v.z = pk2(f1.x,f1.y); v.w = pk2(f1.z,f1.w);
                *reinterpret_cast<int4*>(bL + q * 512 + lane * 8) = v;
            }
        }
        __syncthreads();

        #pragma unroll
        for (int ks = 0; ks < 2; ++ks){
            int sl = ((ks * 4 + fg) ^ fr7) * 8;
            bf16x8 a[4], b[4];
            #pragma unroll
            for (int mi = 0; mi < 4; ++mi)
                a[mi] = *reinterpret_cast<const bf16x8*>(&aS[(wm + mi * 16 + fr) * 64 + sl]);
            #pragma unroll
            for (int ni = 0; ni < 4; ++ni)
                b[ni] = *reinterpret_cast<const bf16x8*>(&bS[(wn + ni * 16 + fr) * 64 + sl]);
            #pragma unroll
            for (int mi = 0; mi < 4; ++mi)
                #pragma unroll
                for (int ni = 0; ni < 4; ++ni)
                    acc[mi][ni] = __builtin_amdgcn_mfma_f32_16x16x32_bf16(a[mi], b[ni], acc[mi][ni], 0, 0, 0);
        }
        __syncthreads();
    }

    #pragma unroll
    for (int mi = 0; mi < 4; ++mi)
        #pragma unroll
        for (int ni = 0; ni < 4; ++ni)
            #pragma unroll
            for (int j = 0; j < 4; ++j){
                int r = wm + mi * 16 + fg * 4 + j;
                int tr = m0 + r;
                if (tr < rows){
                    int c = wn + ni * 16 + fr;
                    ybuf[(size_t)(hoff + tr) * DD + n0 + c] = acc[mi][ni][j];
                }
            }
}

// ---------------- combine: out[n] = g0*ybuf[slot0] + g1*ybuf[slot1] ----------------
__global__ __launch_bounds__(256) void combine_kernel(const float* __restrict__ ybuf,
        const int* __restrict__ islot, const int* __restrict__ offs,
        const float* __restrict__ glist, float* __restrict__ out){
    int idx = blockIdx.x * 256 + threadIdx.x;   // 4096 tokens * 128 (8 cols each)
    int n = idx >> 7, c = (idx & 127) * 8;
    int id0 = islot[n * 2], id1 = islot[n * 2 + 1];
    int r0 = offs[id0 >> 12] + (id0 & 4095);
    int r1 = offs[id1 >> 12] + (id1 & 4095);
    float g0 = glist[id0], g1 = glist[id1];
    const float4* y0 = reinterpret_cast<const float4*>(ybuf + (size_t)r0 * DD + c);
    const float4* y1 = reinterpret_cast<const float4*>(ybuf + (size_t)r1 * DD + c);
    float4 a0 = y0[0], a1 = y0[1], b0 = y1[0], b1 = y1[1];
    float4 o0, o1;
    o0.x = g0 * a0.x + g1 * b0.x; o0.y = g0 * a0.y + g1 * b0.y;
    o0.z = g0 * a0.z + g1 * b0.z; o0.w = g0 * a0.w + g1 * b0.w;
    o1.x = g0 * a1.x + g1 * b1.x; o1.y = g0 * a1.y + g1 * b1.y;
    o1.z = g0 * a1.z + g1 * b1.z; o1.w = g0 * a1.w + g1 * b1.w;
    float4* op = reinterpret_cast<float4*>(out + (size_t)n * DD + c);
    op[0] = o0; op[1] = o1;
}

// ---------------- launch ----------------
// ws layout (bytes):
//   [0,        33554432)  hbuf  : 8192 x 2048 bf16
//   [33554432, 41943040)  xb    : 4096 x 1024 bf16
//   [41943040, 42074112)  list  : 8 x 4096 int
//   [42074112, 42205184)  glist : 8 x 4096 f32
//   [42205184, 42205312)  counters: cnt/offs/psum/cnt1
//   [42205312, 42238080)  islot : 4096 x 2 int
//   [42238208, +32MB)     w1b  (bf16)  -- ybuf (fp32 8192x1024) overlays this after ffn1
//   [+32MB,    +64MB)     w2b  (bf16)
//   [+64MB,    +96MB)     w3b  (bf16)      NEED_FULL = 142,901,504 B
extern "C" void kernel_launch(void* const* d_in, const int* in_sizes, int n_in,
                              void* d_out, int out_size, void* d_ws, size_t ws_size,
                              hipStream_t stream) {
    const float* x  = (const float*)d_in[0];
    const float* Wr = (const float*)d_in[1];
    const float* W1 = (const float*)d_in[2];
    const float* W2 = (const float*)d_in[3];
    const float* W3 = (const float*)d_in[4];
    float* out = (float*)d_out;

    char* wp = (char*)d_ws;
    u16*   hbuf  = (u16*)  (wp);
    u16*   xb    = (u16*)  (wp + 33554432);
    int*   list  = (int*)  (wp + 41943040);
    float* glist = (float*)(wp + 42074112);
    int*   cnt   = (int*)  (wp + 42205184);
    int*   offs  = (int*)  (wp + 42205216);
    float* psum  = (float*)(wp + 42205248);
    int*   cnt1  = (int*)  (wp + 42205280);
    int*   islot = (int*)  (wp + 42205312);
    const size_t WOFF = 42238208;
    const size_t WB   = 33554432;
    u16* w1b = (u16*)(wp + WOFF);
    u16* w2b = (u16*)(wp + WOFF + WB);
    u16* w3b = (u16*)(wp + WOFF + 2 * WB);
    float* ybuf = (float*)(wp + WOFF);           // overlays w1b (dead after ffn1)
    const size_t NEED_FULL = WOFF + 3 * WB;
    bool bw = ws_size >= NEED_FULL;

    hipMemsetAsync(wp + 42205184, 0, 128, stream);

    cvt_all_kernel<<<dim3(NE * HH * DD / 4 / 256, bw ? 4 : 1), 256, 0, stream>>>(
        x, W1, W2, W3, xb, w1b, w2b, w3b);
    router_kernel<<<NTOK / 16, 256, 0, stream>>>(x, Wr, cnt, list, glist, psum, cnt1, islot);
    finalize_kernel<<<1, 64, 0, stream>>>(cnt, offs, psum, cnt1, out + (size_t)NTOK * DD);
    if (bw){
        ffn1_kernel<1><<<4096, 256, 0, stream>>>(xb, w1b, w3b, W1, W3, cnt, offs, list, hbuf);
        ffn2_kernel<1><<<2048, 256, 0, stream>>>(hbuf, w2b, W2, cnt, offs, ybuf);
    } else {
        ffn1_kernel<0><<<4096, 256, 0, stream>>>(xb, w1b, w3b, W1, W3, cnt, offs, list, hbuf);
        ffn2_kernel<0><<<2048, 256, 0, stream>>>(hbuf, w2b, W2, cnt, offs, ybuf);
    }
    combine_kernel<<<NTOK * (DD / 8) / 256, 256, 0, stream>>>(ybuf, islot, offs, glist, out);
}

// Round 5
// 258.153 us; speedup vs baseline: 2.1962x; 2.1962x over previous
//
#include <hip/hip_runtime.h>
#include <stdint.h>

#define NTOK 4096
#define DD 1024
#define HH 2048
#define NE 8
#define CAP 4096

typedef short bf16x8 __attribute__((ext_vector_type(8)));
typedef float f32x4 __attribute__((ext_vector_type(4)));
typedef unsigned short u16;
typedef unsigned int u32;

__device__ __forceinline__ u16 f2b(float f){
    union { float f; u32 u; } v; v.f = f;
    return (u16)((v.u + 0x7fffu + ((v.u >> 16) & 1u)) >> 16);
}
__device__ __forceinline__ u32 pk2(float a, float b){
    return (u32)f2b(a) | ((u32)f2b(b) << 16);
}
// async global->LDS, 16B per lane; LDS dest = wave-uniform base + lane*16
__device__ __forceinline__ void gload16(const u16* g, u16* l){
    __builtin_amdgcn_global_load_lds((const __attribute__((address_space(1))) u32*)g,
                                     (__attribute__((address_space(3))) u32*)l, 16, 0, 0);
}

// ---------------- fp32 -> bf16 bulk converts (x, W1, W2, W3) ----------------
__global__ __launch_bounds__(256) void cvt_all_kernel(const float* __restrict__ x,
        const float* __restrict__ W1, const float* __restrict__ W2, const float* __restrict__ W3,
        u16* __restrict__ xb, u16* __restrict__ w1b, u16* __restrict__ w2b, u16* __restrict__ w3b){
    int y = blockIdx.y;
    const float* s; u16* d; int n4;
    if (y == 0){ s = x;  d = xb;  n4 = NTOK * DD / 4; }
    else if (y == 1){ s = W1; d = w1b; n4 = NE * HH * DD / 4; }
    else if (y == 2){ s = W2; d = w2b; n4 = NE * HH * DD / 4; }
    else { s = W3; d = w3b; n4 = NE * HH * DD / 4; }
    int i = blockIdx.x * 256 + threadIdx.x;
    if (i >= n4) return;
    float4 v = reinterpret_cast<const float4*>(s)[i];
    ushort4 o; o.x = f2b(v.x); o.y = f2b(v.y); o.z = f2b(v.z); o.w = f2b(v.w);
    reinterpret_cast<ushort4*>(d)[i] = o;
}

// ---------------- router (fp32, block-aggregated atomics) ----------------
__global__ __launch_bounds__(256) void router_kernel(const float* __restrict__ x,
                              const float* __restrict__ Wr,
                              int* __restrict__ cnt, int* __restrict__ list,
                              float* __restrict__ glist, float* __restrict__ psum,
                              int* __restrict__ cnt1, int* __restrict__ islot){
    __shared__ float wS[NE * DD];
    __shared__ float psumS[NE];
    __shared__ int cnt1S[NE], cntS[NE], baseS[NE];
    __shared__ int tE[32], tL[32];
    __shared__ float tP[32];
    int tid = threadIdx.x;
    for (int i = tid; i < NE * DD / 4; i += 256)
        reinterpret_cast<float4*>(wS)[i] = reinterpret_cast<const float4*>(Wr)[i];
    if (tid < NE){ psumS[tid] = 0.f; cnt1S[tid] = 0; cntS[tid] = 0; }
    __syncthreads();
    int lane = tid & 63, w = tid >> 6;
    for (int t = 0; t < 4; ++t){
        int li = w * 4 + t;
        int n = blockIdx.x * 16 + li;
        const float4* xr = reinterpret_cast<const float4*>(x + (size_t)n * DD);
        float acc[NE];
        #pragma unroll
        for (int e = 0; e < NE; ++e) acc[e] = 0.f;
        #pragma unroll
        for (int j = 0; j < 4; ++j){
            float4 xv = xr[lane + 64 * j];
            #pragma unroll
            for (int e = 0; e < NE; ++e){
                float4 wv = reinterpret_cast<const float4*>(wS + e * DD)[lane + 64 * j];
                acc[e] += xv.x * wv.x + xv.y * wv.y + xv.z * wv.z + xv.w * wv.w;
            }
        }
        #pragma unroll
        for (int e = 0; e < NE; ++e){
            float v = acc[e];
            #pragma unroll
            for (int s = 32; s > 0; s >>= 1) v += __shfl_xor(v, s);
            acc[e] = v;
        }
        if (lane == 0){
            float mx = acc[0];
            #pragma unroll
            for (int e = 1; e < NE; ++e) mx = fmaxf(mx, acc[e]);
            float p[NE], sm = 0.f;
            #pragma unroll
            for (int e = 0; e < NE; ++e){ p[e] = expf(acc[e] - mx); sm += p[e]; }
            float inv = 1.f / sm;
            #pragma unroll
            for (int e = 0; e < NE; ++e){ p[e] *= inv; atomicAdd(&psumS[e], p[e]); }
            int i0 = 0;
            #pragma unroll
            for (int e = 1; e < NE; ++e) if (acc[e] > acc[i0]) i0 = e;
            int i1 = -1;
            #pragma unroll
            for (int e = 0; e < NE; ++e) if (e != i0 && (i1 < 0 || acc[e] > acc[i1])) i1 = e;
            atomicAdd(&cnt1S[i0], 1);
            int l0 = atomicAdd(&cntS[i0], 1);
            int l1 = atomicAdd(&cntS[i1], 1);
            tE[li * 2] = i0; tE[li * 2 + 1] = i1;
            tP[li * 2] = p[i0]; tP[li * 2 + 1] = p[i1];
            tL[li * 2] = l0; tL[li * 2 + 1] = l1;
        }
    }
    __syncthreads();
    if (tid < NE){
        baseS[tid] = atomicAdd(&cnt[tid], cntS[tid]);
        atomicAdd(&psum[tid], psumS[tid]);
        atomicAdd(&cnt1[tid], cnt1S[tid]);
    }
    __syncthreads();
    if (tid < 32){
        int e = tE[tid], pos = baseS[e] + tL[tid];
        int n = blockIdx.x * 16 + (tid >> 1);
        list[e * CAP + pos]  = n;
        glist[e * CAP + pos] = tP[tid];
        islot[n * 2 + (tid & 1)] = e * CAP + pos;
    }
}

// ---------------- prefix offsets + aux loss ----------------
__global__ void finalize_kernel(const int* __restrict__ cnt, int* __restrict__ offs,
                                const float* __restrict__ psum, const int* __restrict__ cnt1,
                                float* __restrict__ aux_out){
    if (threadIdx.x == 0 && blockIdx.x == 0){
        int o = 0; float aux = 0.f;
        for (int e = 0; e < NE; ++e){
            offs[e] = o; o += cnt[e];
            aux += ((float)cnt1[e] * (1.f / NTOK)) * (psum[e] * (1.f / NTOK));
        }
        aux_out[0] = 0.01f * aux * (float)NE;
    }
}

// ---------------- GEMM1: h = silu(X W1^T) * (X W3^T) ----------------
// 128x128x64 tiles, XOR-swizzled LDS (pre-swizzled global source, swizzled read),
// global_load_lds staging, XCD swizzle (expert per XCD, mt-fastest)
// launch_bounds (256,2): ~84 VGPR + 128 acc regs = ~212/wave; 2 waves/SIMD fits 512 pool, 3 would spill (R4 lesson)
template<int BW>
__global__ __launch_bounds__(256, 2) void ffn1_kernel(const u16* __restrict__ xb,
        const u16* __restrict__ w1b, const u16* __restrict__ w3b,
        const float* __restrict__ W1f, const float* __restrict__ W3f,
        const int* __restrict__ cnt, const int* __restrict__ offs,
        const int* __restrict__ list, u16* __restrict__ hbuf){
    int bid = blockIdx.x;                       // 4096 = 8e * 16n * 32mt
    int widx = (bid & 7) * 512 + (bid >> 3);    // bijective: XCD bid%8 gets 512 consecutive work items
    int e = widx >> 9, n0t = (widx >> 5) & 15, mt = widx & 31;
    int rows = cnt[e];
    int m0 = mt * 128;
    if (m0 >= rows) return;
    int n0 = n0t * 128;

    __shared__ u16 aS[128 * 64];
    __shared__ u16 b1S[128 * 64];
    __shared__ u16 b3S[128 * 64];

    int tid = threadIdx.x, lane = tid & 63, w = tid >> 6;
    int wm = (w & 1) * 64, wn = (w >> 1) * 64;
    int fr = lane & 15, fg = lane >> 4;
    int fr7 = fr & 7;
    int rc = lane >> 3;                          // row-in-chunk (0..7)
    int ce = ((lane & 7) ^ rc) * 8;              // XOR-swizzled source col (16B units)

    const u16* aptr[4];
    #pragma unroll
    for (int q = 0; q < 4; ++q){
        int r = m0 + (w * 4 + q) * 8 + rc;
        int tok = list[e * CAP + (r < rows ? r : rows - 1)];
        aptr[q] = xb + (size_t)tok * DD + ce;
    }
    size_t brow = (size_t)(e * HH + n0 + w * 32 + rc) * DD + ce;
    const u16*   b1p  = w1b + brow;
    const u16*   b3p  = w3b + brow;
    const float* b1pf = W1f + brow;
    const float* b3pf = W3f + brow;
    u16* aL  = aS  + w * 4 * 512;               // chunk = 8 rows x 64 cols = 512 elems (1KB)
    u16* b1L = b1S + w * 4 * 512;
    u16* b3L = b3S + w * 4 * 512;

    f32x4 acc1[4][4], acc3[4][4];
    #pragma unroll
    for (int mi = 0; mi < 4; ++mi)
        #pragma unroll
        for (int ni = 0; ni < 4; ++ni)
            #pragma unroll
            for (int j = 0; j < 4; ++j){ acc1[mi][ni][j] = 0.f; acc3[mi][ni][j] = 0.f; }

    for (int k0 = 0; k0 < DD; k0 += 64){
        #pragma unroll
        for (int q = 0; q < 4; ++q){
            gload16(aptr[q] + k0, aL + q * 512);
            if (BW){
                gload16(b1p + q * 8 * DD + k0, b1L + q * 512);
                gload16(b3p + q * 8 * DD + k0, b3L + q * 512);
            } else {
                const float* s1 = b1pf + q * 8 * DD + k0;
                float4 f0 = reinterpret_cast<const float4*>(s1)[0];
                float4 f1 = reinterpret_cast<const float4*>(s1)[1];
                int4 v; v.x = pk2(f0.x,f0.y); v.y = pk2(f0.z,f0.w); v.z = pk2(f1.x,f1.y); v.w = pk2(f1.z,f1.w);
                *reinterpret_cast<int4*>(b1L + q * 512 + lane * 8) = v;
                const float* s3 = b3pf + q * 8 * DD + k0;
                float4 g0 = reinterpret_cast<const float4*>(s3)[0];
                float4 g1 = reinterpret_cast<const float4*>(s3)[1];
                int4 u; u.x = pk2(g0.x,g0.y); u.y = pk2(g0.z,g0.w); u.z = pk2(g1.x,g1.y); u.w = pk2(g1.z,g1.w);
                *reinterpret_cast<int4*>(b3L + q * 512 + lane * 8) = u;
            }
        }
        __syncthreads();

        #pragma unroll
        for (int ks = 0; ks < 2; ++ks){
            int sl = ((ks * 4 + fg) ^ fr7) * 8;  // swizzled 16B-slot within row
            bf16x8 a[4], b1[4], b3[4];
            #pragma unroll
            for (int mi = 0; mi < 4; ++mi)
                a[mi] = *reinterpret_cast<const bf16x8*>(&aS[(wm + mi * 16 + fr) * 64 + sl]);
            #pragma unroll
            for (int ni = 0; ni < 4; ++ni){
                b1[ni] = *reinterpret_cast<const bf16x8*>(&b1S[(wn + ni * 16 + fr) * 64 + sl]);
                b3[ni] = *reinterpret_cast<const bf16x8*>(&b3S[(wn + ni * 16 + fr) * 64 + sl]);
            }
            #pragma unroll
            for (int mi = 0; mi < 4; ++mi)
                #pragma unroll
                for (int ni = 0; ni < 4; ++ni){
                    acc1[mi][ni] = __builtin_amdgcn_mfma_f32_16x16x32_bf16(a[mi], b1[ni], acc1[mi][ni], 0, 0, 0);
                    acc3[mi][ni] = __builtin_amdgcn_mfma_f32_16x16x32_bf16(a[mi], b3[ni], acc3[mi][ni], 0, 0, 0);
                }
        }
        __syncthreads();
    }

    int hoff = offs[e];
    #pragma unroll
    for (int mi = 0; mi < 4; ++mi)
        #pragma unroll
        for (int ni = 0; ni < 4; ++ni)
            #pragma unroll
            for (int j = 0; j < 4; ++j){
                int r = wm + mi * 16 + fg * 4 + j;
                int tr = m0 + r;
                if (tr < rows){
                    int c = wn + ni * 16 + fr;
                    float v1 = acc1[mi][ni][j], v3 = acc3[mi][ni][j];
                    float hv = (v1 / (1.f + expf(-v1))) * v3;
                    hbuf[(size_t)(hoff + tr) * HH + n0 + c] = f2b(hv);
                }
            }
}

// ---------------- GEMM2: y = h W2^T -> ybuf (fp32, slot rows) ----------------
// launch_bounds (256,2): ~84 VGPR + 64 acc = ~148/wave; safe at 2 waves/SIMD (R4: 4 spilled)
template<int BW>
__global__ __launch_bounds__(256, 2) void ffn2_kernel(const u16* __restrict__ hbuf,
        const u16* __restrict__ w2b, const float* __restrict__ W2f,
        const int* __restrict__ cnt, const int* __restrict__ offs,
        float* __restrict__ ybuf){
    int bid = blockIdx.x;                       // 2048 = 8e * 8n * 32mt
    int widx = (bid & 7) * 256 + (bid >> 3);
    int e = widx >> 8, n0t = (widx >> 5) & 7, mt = widx & 31;
    int rows = cnt[e];
    int m0 = mt * 128;
    if (m0 >= rows) return;
    int n0 = n0t * 128;

    __shared__ u16 aS[128 * 64];
    __shared__ u16 bS[128 * 64];

    int tid = threadIdx.x, lane = tid & 63, w = tid >> 6;
    int wm = (w & 1) * 64, wn = (w >> 1) * 64;
    int fr = lane & 15, fg = lane >> 4;
    int fr7 = fr & 7;
    int rc = lane >> 3;
    int ce = ((lane & 7) ^ rc) * 8;

    int hoff = offs[e];
    const u16* aptr[4];
    #pragma unroll
    for (int q = 0; q < 4; ++q){
        int r = m0 + (w * 4 + q) * 8 + rc;
        if (r >= rows) r = rows - 1;
        aptr[q] = hbuf + (size_t)(hoff + r) * HH + ce;
    }
    size_t brow = (size_t)(e * DD + n0 + w * 32 + rc) * HH + ce;
    const u16*   b2p  = w2b + brow;
    const float* b2pf = W2f + brow;
    u16* aL = aS + w * 4 * 512;
    u16* bL = bS + w * 4 * 512;

    f32x4 acc[4][4];
    #pragma unroll
    for (int mi = 0; mi < 4; ++mi)
        #pragma unroll
        for (int ni = 0; ni < 4; ++ni)
            #pragma unroll
            for (int j = 0; j < 4; ++j) acc[mi][ni][j] = 0.f;

    for (int k0 = 0; k0 < HH; k0 += 64){
        #pragma unroll
        for (int q = 0; q < 4; ++q){
            gload16(aptr[q] + k0, aL + q * 512);
            if (BW){
                gload16(b2p + q * 8 * HH + k0, bL + q * 512);
            } else {
                const float* s2 = b2pf + q * 8 * HH + k0;
                float4 f0 = reinterpret_cast<const float4*>(s2)[0];
                float4 f1 = reinterpret_cast<const float4*>(s2)[1];
                int4 v; v.x = pk2(f0.x,f0.y); v.y = pk2(f0.z,f0.w); v.z = pk2(f1.x,f1.y); v.w = pk2(f1.z,f1.w);
                *reinterpret_cast<int4*>(bL + q * 512 + lane * 8) = v;
            }
        }
        __syncthreads();

        #pragma unroll
        for (int ks = 0; ks < 2; ++ks){
            int sl = ((ks * 4 + fg) ^ fr7) * 8;
            bf16x8 a[4], b[4];
            #pragma unroll
            for (int mi = 0; mi < 4; ++mi)
                a[mi] = *reinterpret_cast<const bf16x8*>(&aS[(wm + mi * 16 + fr) * 64 + sl]);
            #pragma unroll
            for (int ni = 0; ni < 4; ++ni)
                b[ni] = *reinterpret_cast<const bf16x8*>(&bS[(wn + ni * 16 + fr) * 64 + sl]);
            #pragma unroll
            for (int mi = 0; mi < 4; ++mi)
                #pragma unroll
                for (int ni = 0; ni < 4; ++ni)
                    acc[mi][ni] = __builtin_amdgcn_mfma_f32_16x16x32_bf16(a[mi], b[ni], acc[mi][ni], 0, 0, 0);
        }
        __syncthreads();
    }

    #pragma unroll
    for (int mi = 0; mi < 4; ++mi)
        #pragma unroll
        for (int ni = 0; ni < 4; ++ni)
            #pragma unroll
            for (int j = 0; j < 4; ++j){
                int r = wm + mi * 16 + fg * 4 + j;
                int tr = m0 + r;
                if (tr < rows){
                    int c = wn + ni * 16 + fr;
                    ybuf[(size_t)(hoff + tr) * DD + n0 + c] = acc[mi][ni][j];
                }
            }
}

// ---------------- combine: out[n] = g0*ybuf[slot0] + g1*ybuf[slot1] ----------------
__global__ __launch_bounds__(256) void combine_kernel(const float* __restrict__ ybuf,
        const int* __restrict__ islot, const int* __restrict__ offs,
        const float* __restrict__ glist, float* __restrict__ out){
    int idx = blockIdx.x * 256 + threadIdx.x;   // 4096 tokens * 128 (8 cols each)
    int n = idx >> 7, c = (idx & 127) * 8;
    int id0 = islot[n * 2], id1 = islot[n * 2 + 1];
    int r0 = offs[id0 >> 12] + (id0 & 4095);
    int r1 = offs[id1 >> 12] + (id1 & 4095);
    float g0 = glist[id0], g1 = glist[id1];
    const float4* y0 = reinterpret_cast<const float4*>(ybuf + (size_t)r0 * DD + c);
    const float4* y1 = reinterpret_cast<const float4*>(ybuf + (size_t)r1 * DD + c);
    float4 a0 = y0[0], a1 = y0[1], b0 = y1[0], b1 = y1[1];
    float4 o0, o1;
    o0.x = g0 * a0.x + g1 * b0.x; o0.y = g0 * a0.y + g1 * b0.y;
    o0.z = g0 * a0.z + g1 * b0.z; o0.w = g0 * a0.w + g1 * b0.w;
    o1.x = g0 * a1.x + g1 * b1.x; o1.y = g0 * a1.y + g1 * b1.y;
    o1.z = g0 * a1.z + g1 * b1.z; o1.w = g0 * a1.w + g1 * b1.w;
    float4* op = reinterpret_cast<float4*>(out + (size_t)n * DD + c);
    op[0] = o0; op[1] = o1;
}

// ---------------- launch ----------------
// ws layout (bytes):
//   [0,        33554432)  hbuf  : 8192 x 2048 bf16
//   [33554432, 41943040)  xb    : 4096 x 1024 bf16
//   [41943040, 42074112)  list  : 8 x 4096 int
//   [42074112, 42205184)  glist : 8 x 4096 f32
//   [42205184, 42205312)  counters: cnt/offs/psum/cnt1
//   [42205312, 42238080)  islot : 4096 x 2 int
//   [42238208, +32MB)     w1b  (bf16)  -- ybuf (fp32 8192x1024) overlays this after ffn1
//   [+32MB,    +64MB)     w2b  (bf16)
//   [+64MB,    +96MB)     w3b  (bf16)      NEED_FULL = 142,901,504 B
extern "C" void kernel_launch(void* const* d_in, const int* in_sizes, int n_in,
                              void* d_out, int out_size, void* d_ws, size_t ws_size,
                              hipStream_t stream) {
    const float* x  = (const float*)d_in[0];
    const float* Wr = (const float*)d_in[1];
    const float* W1 = (const float*)d_in[2];
    const float* W2 = (const float*)d_in[3];
    const float* W3 = (const float*)d_in[4];
    float* out = (float*)d_out;

    char* wp = (char*)d_ws;
    u16*   hbuf  = (u16*)  (wp);
    u16*   xb    = (u16*)  (wp + 33554432);
    int*   list  = (int*)  (wp + 41943040);
    float* glist = (float*)(wp + 42074112);
    int*   cnt   = (int*)  (wp + 42205184);
    int*   offs  = (int*)  (wp + 42205216);
    float* psum  = (float*)(wp + 42205248);
    int*   cnt1  = (int*)  (wp + 42205280);
    int*   islot = (int*)  (wp + 42205312);
    const size_t WOFF = 42238208;
    const size_t WB   = 33554432;
    u16* w1b = (u16*)(wp + WOFF);
    u16* w2b = (u16*)(wp + WOFF + WB);
    u16* w3b = (u16*)(wp + WOFF + 2 * WB);
    float* ybuf = (float*)(wp + WOFF);           // overlays w1b (dead after ffn1)
    const size_t NEED_FULL = WOFF + 3 * WB;
    bool bw = ws_size >= NEED_FULL;

    hipMemsetAsync(wp + 42205184, 0, 128, stream);

    cvt_all_kernel<<<dim3(NE * HH * DD / 4 / 256, bw ? 4 : 1), 256, 0, stream>>>(
        x, W1, W2, W3, xb, w1b, w2b, w3b);
    router_kernel<<<NTOK / 16, 256, 0, stream>>>(x, Wr, cnt, list, glist, psum, cnt1, islot);
    finalize_kernel<<<1, 64, 0, stream>>>(cnt, offs, psum, cnt1, out + (size_t)NTOK * DD);
    if (bw){
        ffn1_kernel<1><<<4096, 256, 0, stream>>>(xb, w1b, w3b, W1, W3, cnt, offs, list, hbuf);
        ffn2_kernel<1><<<2048, 256, 0, stream>>>(hbuf, w2b, W2, cnt, offs, ybuf);
    } else {
        ffn1_kernel<0><<<4096, 256, 0, stream>>>(xb, w1b, w3b, W1, W3, cnt, offs, list, hbuf);
        ffn2_kernel<0><<<2048, 256, 0, stream>>>(hbuf, w2b, W2, cnt, offs, ybuf);
    }
    combine_kernel<<<NTOK * (DD / 8) / 256, 256, 0, stream>>>(ybuf, islot, offs, glist, out);
}